// Round 1
// baseline (828.236 us; speedup 1.0000x reference)
//
#include <hip/hip_runtime.h>
#include <hip/hip_bf16.h>

typedef unsigned short u16;
typedef __attribute__((ext_vector_type(8))) short bf16x8;   // 8 bf16 in 4 VGPRs
typedef __attribute__((ext_vector_type(4))) float f32x4;

#define DEV static __device__ __forceinline__

#define BB 16
#define NN 1024
#define EE 768
#define HH 12
#define DD 64
#define BN (BB*NN)   // 16384

DEV u16 f2bf(float f){ __hip_bfloat16 h = __float2bfloat16(f); u16 u; __builtin_memcpy(&u, &h, 2); return u; }
DEV float bf2f(u16 u){ __hip_bfloat16 h; __builtin_memcpy(&h, &u, 2); return __bfloat162float(h); }
DEV void split2(float v, u16& hi, u16& lo){ hi = f2bf(v); lo = f2bf(v - bf2f(hi)); }
DEV bf16x8 ld8(const u16* p){ return *(const bf16x8*)p; }
DEV f32x4 mfma16(bf16x8 a, bf16x8 b, f32x4 c){ return __builtin_amdgcn_mfma_f32_16x16x32_bf16(a, b, c, 0, 0, 0); }

// ---------------- prep kernels ----------------

// split x (fp32) into bf16 hi/lo pair; 4 elems/thread, exact grid
__global__ __launch_bounds__(256) void split_x_k(const float* __restrict__ x,
                                                 u16* __restrict__ xh, u16* __restrict__ xl){
  int i = blockIdx.x*256 + threadIdx.x;          // < 3145728
  const float4 v = ((const float4*)x)[i];
  ushort4 h, l;
  split2(v.x, h.x, l.x);
  split2(v.y, h.y, l.y);
  split2(v.z, h.z, l.z);
  split2(v.w, h.w, l.w);
  ((ushort4*)xh)[i] = h;
  ((ushort4*)xl)[i] = l;
}

// W [h][e][d] fp32 -> Wt [h][d][e] bf16 hi(/lo), scale folded (1/8 for Wq)
__global__ __launch_bounds__(256) void pack_w_k(const float* __restrict__ W,
                                                u16* __restrict__ Wh, u16* __restrict__ Wl,
                                                float scale, int dosplit){
  int i = blockIdx.x*256 + threadIdx.x;          // < 589824
  int d = i & 63; int he = i >> 6; int h = he / EE; int e = he - h*EE;
  float v = W[i]*scale;
  u16 hi, lo; split2(v, hi, lo);
  size_t o = (size_t)(h*DD + d)*EE + e;
  Wh[o] = hi;
  if (dosplit) Wl[o] = lo;
}

// Wo [H*D][D] fp32 -> Wot [D][H*D] bf16
__global__ __launch_bounds__(256) void pack_wo_k(const float* __restrict__ W, u16* __restrict__ Wt){
  int i = blockIdx.x*256 + threadIdx.x;          // < 49152
  int j = i & 63, k = i >> 6;
  Wt[(size_t)j*EE + k] = f2bf(W[i]);
}

// ---------------- projection GEMMs ----------------
// Q/K: C[h][n][d] = sum_e X[n][e]*W[h][e][d], 3-pass hi/lo split, output split to hi/lo bf16.
// 128 rows x 64 cols per block, 4 waves (32 rows each). Frags direct from global (L2-hot).
__global__ __launch_bounds__(256) void gemm_qk_k(const u16* __restrict__ Xh, const u16* __restrict__ Xl,
                                                 const u16* __restrict__ Wh, const u16* __restrict__ Wl,
                                                 u16* __restrict__ Oh, u16* __restrict__ Ol){
  const int rt = blockIdx.x, h = blockIdx.y;
  const int w = threadIdx.x >> 6, l = threadIdx.x & 63, lr = l & 15, lg = l >> 4;
  const int row0 = rt*128 + w*32;
  const u16* wh = Wh + (size_t)h*DD*EE;
  const u16* wl = Wl + (size_t)h*DD*EE;
  f32x4 acc[2][4];
  #pragma unroll
  for (int m=0;m<2;++m)
    #pragma unroll
    for (int n=0;n<4;++n) acc[m][n] = f32x4{0.f,0.f,0.f,0.f};

  for (int kt=0; kt<12; ++kt){
    const int e0 = kt*64;
    bf16x8 ah[2][2], al[2][2], bh[4][2], bl[4][2];
    #pragma unroll
    for (int m=0;m<2;++m)
      #pragma unroll
      for (int ks=0;ks<2;++ks){
        size_t o = (size_t)(row0 + m*16 + lr)*EE + e0 + ks*32 + lg*8;
        ah[m][ks] = ld8(Xh + o);
        al[m][ks] = ld8(Xl + o);
      }
    #pragma unroll
    for (int nf=0;nf<4;++nf)
      #pragma unroll
      for (int ks=0;ks<2;++ks){
        size_t o = (size_t)(nf*16 + lr)*EE + e0 + ks*32 + lg*8;
        bh[nf][ks] = ld8(wh + o);
        bl[nf][ks] = ld8(wl + o);
      }
    #pragma unroll
    for (int ks=0;ks<2;++ks)
      #pragma unroll
      for (int m=0;m<2;++m)
        #pragma unroll
        for (int nf=0;nf<4;++nf){
          acc[m][nf] = mfma16(ah[m][ks], bh[nf][ks], acc[m][nf]);
          acc[m][nf] = mfma16(ah[m][ks], bl[nf][ks], acc[m][nf]);
          acc[m][nf] = mfma16(al[m][ks], bh[nf][ks], acc[m][nf]);
        }
  }
  const size_t ob = (size_t)h*BN*DD;
  #pragma unroll
  for (int m=0;m<2;++m)
    #pragma unroll
    for (int nf=0;nf<4;++nf)
      #pragma unroll
      for (int j=0;j<4;++j){
        u16 hi, lo; split2(acc[m][nf][j], hi, lo);
        size_t o = ob + (size_t)(row0 + m*16 + lg*4 + j)*DD + nf*16 + lr;
        Oh[o] = hi; Ol[o] = lo;
      }
}

// V: single-pass bf16, stored transposed Vt[h][b][d][n]
__global__ __launch_bounds__(256) void gemm_v_k(const u16* __restrict__ Xh,
                                                const u16* __restrict__ Wh,
                                                u16* __restrict__ Vt){
  const int rt = blockIdx.x, h = blockIdx.y;
  const int w = threadIdx.x >> 6, l = threadIdx.x & 63, lr = l & 15, lg = l >> 4;
  const int row0 = rt*128 + w*32;
  const u16* wh = Wh + (size_t)h*DD*EE;
  f32x4 acc[2][4];
  #pragma unroll
  for (int m=0;m<2;++m)
    #pragma unroll
    for (int n=0;n<4;++n) acc[m][n] = f32x4{0.f,0.f,0.f,0.f};

  for (int kt=0; kt<12; ++kt){
    const int e0 = kt*64;
    bf16x8 ah[2][2], bh[4][2];
    #pragma unroll
    for (int m=0;m<2;++m)
      #pragma unroll
      for (int ks=0;ks<2;++ks)
        ah[m][ks] = ld8(Xh + (size_t)(row0 + m*16 + lr)*EE + e0 + ks*32 + lg*8);
    #pragma unroll
    for (int nf=0;nf<4;++nf)
      #pragma unroll
      for (int ks=0;ks<2;++ks)
        bh[nf][ks] = ld8(wh + (size_t)(nf*16 + lr)*EE + e0 + ks*32 + lg*8);
    #pragma unroll
    for (int ks=0;ks<2;++ks)
      #pragma unroll
      for (int m=0;m<2;++m)
        #pragma unroll
        for (int nf=0;nf<4;++nf)
          acc[m][nf] = mfma16(ah[m][ks], bh[nf][ks], acc[m][nf]);
  }
  #pragma unroll
  for (int m=0;m<2;++m)
    #pragma unroll
    for (int nf=0;nf<4;++nf){
      ushort4 pk;
      pk.x = f2bf(acc[m][nf][0]); pk.y = f2bf(acc[m][nf][1]);
      pk.z = f2bf(acc[m][nf][2]); pk.w = f2bf(acc[m][nf][3]);
      int ng = row0 + m*16 + lg*4;
      int b = ng >> 10, n = ng & 1023;
      *(ushort4*)(Vt + ((size_t)((h*16 + b)*DD + nf*16 + lr))*NN + n) = pk;
    }
}

// ---------------- flash attention ----------------
// grid: B*H*(N/128) = 1536 blocks, 4 waves, 32 q-rows/wave, KV tiles of 64.
__global__ __launch_bounds__(256) void flash_k(const u16* __restrict__ Qh, const u16* __restrict__ Ql,
                                               const u16* __restrict__ Kh, const u16* __restrict__ Kl,
                                               const u16* __restrict__ Vt, u16* __restrict__ Cc){
  __shared__ char pbuf[4][4096];      // per-wave swizzled P tile [32][64] bf16
  const int gid = blockIdx.x;
  const int qb = gid & 7, h = (gid >> 3) % 12, b = gid / 96;
  const int w = threadIdx.x >> 6, l = threadIdx.x & 63, lr = l & 15, lg = l >> 4;
  char* pb = pbuf[w];
  const size_t hb = (size_t)h*BN*DD + (size_t)b*NN*DD;
  const size_t vtb = (size_t)((h*16 + b)*DD);
  const int q0 = qb*128 + w*32;

  // hoist Q frags (A-layout: row = l&15, k = lg*8..)
  bf16x8 qh[2][2], qlv[2][2];
  #pragma unroll
  for (int m=0;m<2;++m)
    #pragma unroll
    for (int ks=0;ks<2;++ks){
      size_t o = hb + (size_t)(q0 + m*16 + lr)*DD + ks*32 + lg*8;
      qh[m][ks]  = ld8(Qh + o);
      qlv[m][ks] = ld8(Ql + o);
    }

  f32x4 acc[2][4];
  float mr[2][4], ls[2][4];
  #pragma unroll
  for (int m=0;m<2;++m)
    #pragma unroll
    for (int nf=0;nf<4;++nf) acc[m][nf] = f32x4{0.f,0.f,0.f,0.f};
  #pragma unroll
  for (int m=0;m<2;++m)
    #pragma unroll
    for (int j=0;j<4;++j){ mr[m][j] = -1e30f; ls[m][j] = 0.f; }

  for (int t=0;t<16;++t){
    const int kv0 = t*64;
    f32x4 s[2][4];
    #pragma unroll
    for (int m=0;m<2;++m)
      #pragma unroll
      for (int nf=0;nf<4;++nf) s[m][nf] = f32x4{0.f,0.f,0.f,0.f};

    // QK^T, 3-pass split
    #pragma unroll
    for (int ks=0;ks<2;++ks){
      bf16x8 kh[4], kl2[4];
      #pragma unroll
      for (int nf=0;nf<4;++nf){
        size_t o = hb + (size_t)(kv0 + nf*16 + lr)*DD + ks*32 + lg*8;
        kh[nf]  = ld8(Kh + o);
        kl2[nf] = ld8(Kl + o);
      }
      #pragma unroll
      for (int m=0;m<2;++m)
        #pragma unroll
        for (int nf=0;nf<4;++nf){
          s[m][nf] = mfma16(qh[m][ks],  kh[nf],  s[m][nf]);
          s[m][nf] = mfma16(qh[m][ks],  kl2[nf], s[m][nf]);
          s[m][nf] = mfma16(qlv[m][ks], kh[nf],  s[m][nf]);
        }
    }

    // online softmax (wave-parallel: 16-lane-group shfl reduce)
    float fsc[2][4];
    #pragma unroll
    for (int m=0;m<2;++m)
      #pragma unroll
      for (int j=0;j<4;++j){
        float rm = fmaxf(fmaxf(s[m][0][j], s[m][1][j]), fmaxf(s[m][2][j], s[m][3][j]));
        #pragma unroll
        for (int d2=1; d2<16; d2<<=1) rm = fmaxf(rm, __shfl_xor(rm, d2, 64));
        float mn = fmaxf(mr[m][j], rm);
        fsc[m][j] = __expf(mr[m][j] - mn);
        mr[m][j] = mn;
      }
    #pragma unroll
    for (int m=0;m<2;++m)
      #pragma unroll
      for (int nf=0;nf<4;++nf)
        #pragma unroll
        for (int j=0;j<4;++j)
          s[m][nf][j] = __expf(s[m][nf][j] - mr[m][j]);
    #pragma unroll
    for (int m=0;m<2;++m)
      #pragma unroll
      for (int j=0;j<4;++j){
        float rs = s[m][0][j] + s[m][1][j] + s[m][2][j] + s[m][3][j];
        #pragma unroll
        for (int d2=1; d2<16; d2<<=1) rs += __shfl_xor(rs, d2, 64);
        ls[m][j] = ls[m][j]*fsc[m][j] + rs;
      }
    #pragma unroll
    for (int m=0;m<2;++m)
      #pragma unroll
      for (int nf=0;nf<4;++nf)
        #pragma unroll
        for (int j=0;j<4;++j)
          acc[m][nf][j] *= fsc[m][j];

    // P -> per-wave LDS (row-major [32][64] bf16, XOR-swizzled bytes)
    #pragma unroll
    for (int m=0;m<2;++m)
      #pragma unroll
      for (int nf=0;nf<4;++nf)
        #pragma unroll
        for (int j=0;j<4;++j){
          int row = m*16 + lg*4 + j;
          *(u16*)(pb + row*128 + (((nf*16 + lr)*2) ^ ((row&7)<<4))) = f2bf(s[m][nf][j]);
        }
    // read P A-frags (swizzled b128)
    bf16x8 pa[2][2];
    #pragma unroll
    for (int m=0;m<2;++m)
      #pragma unroll
      for (int ks=0;ks<2;++ks){
        int row = m*16 + lr;
        pa[m][ks] = *(const bf16x8*)(pb + row*128 + ((ks*64 + lg*16) ^ ((row&7)<<4)));
      }
    // V B-frags from transposed Vt (contiguous along kv)
    bf16x8 vb[4][2];
    #pragma unroll
    for (int nf=0;nf<4;++nf)
      #pragma unroll
      for (int ks=0;ks<2;++ks)
        vb[nf][ks] = ld8(Vt + (vtb + nf*16 + lr)*NN + kv0 + ks*32 + lg*8);
    #pragma unroll
    for (int ks=0;ks<2;++ks)
      #pragma unroll
      for (int m=0;m<2;++m)
        #pragma unroll
        for (int nf=0;nf<4;++nf)
          acc[m][nf] = mfma16(pa[m][ks], vb[nf][ks], acc[m][nf]);
  }

  // epilogue: normalize, write concat [B*N][H*D] bf16
  #pragma unroll
  for (int m=0;m<2;++m)
    #pragma unroll
    for (int j=0;j<4;++j){
      float inv = 1.0f / ls[m][j];
      #pragma unroll
      for (int nf=0;nf<4;++nf)
        Cc[(size_t)(b*NN + q0 + m*16 + lg*4 + j)*EE + h*DD + nf*16 + lr] = f2bf(acc[m][nf][j]*inv);
    }
}

// ---------------- output projection ----------------
__global__ __launch_bounds__(256) void gemm_o_k(const u16* __restrict__ Cc, const u16* __restrict__ Wot,
                                                float* __restrict__ out){
  const int rt = blockIdx.x;
  const int w = threadIdx.x >> 6, l = threadIdx.x & 63, lr = l & 15, lg = l >> 4;
  const int row0 = rt*128 + w*32;
  f32x4 acc[2][4];
  #pragma unroll
  for (int m=0;m<2;++m)
    #pragma unroll
    for (int n=0;n<4;++n) acc[m][n] = f32x4{0.f,0.f,0.f,0.f};

  for (int kt=0; kt<12; ++kt){
    const int e0 = kt*64;
    bf16x8 a[2][2], bb[4][2];
    #pragma unroll
    for (int m=0;m<2;++m)
      #pragma unroll
      for (int ks=0;ks<2;++ks)
        a[m][ks] = ld8(Cc + (size_t)(row0 + m*16 + lr)*EE + e0 + ks*32 + lg*8);
    #pragma unroll
    for (int nf=0;nf<4;++nf)
      #pragma unroll
      for (int ks=0;ks<2;++ks)
        bb[nf][ks] = ld8(Wot + (size_t)(nf*16 + lr)*EE + e0 + ks*32 + lg*8);
    #pragma unroll
    for (int ks=0;ks<2;++ks)
      #pragma unroll
      for (int m=0;m<2;++m)
        #pragma unroll
        for (int nf=0;nf<4;++nf)
          acc[m][nf] = mfma16(a[m][ks], bb[nf][ks], acc[m][nf]);
  }
  #pragma unroll
  for (int m=0;m<2;++m)
    #pragma unroll
    for (int nf=0;nf<4;++nf)
      #pragma unroll
      for (int j=0;j<4;++j)
        out[(size_t)(row0 + m*16 + lg*4 + j)*DD + nf*16 + lr] = acc[m][nf][j];
}

// ---------------- launch ----------------
extern "C" void kernel_launch(void* const* d_in, const int* in_sizes, int n_in,
                              void* d_out, int out_size, void* d_ws, size_t ws_size,
                              hipStream_t stream) {
  const float* x  = (const float*)d_in[0];
  const float* Wq = (const float*)d_in[1];
  const float* Wk = (const float*)d_in[2];
  const float* Wv = (const float*)d_in[3];
  const float* Wo = (const float*)d_in[4];
  float* out = (float*)d_out;

  // workspace layout (u16 elems). total = 8*12582912 + 5*589824 + 49152 = 103,661,568 elems = ~198 MiB
  u16* ws = (u16*)d_ws;
  const size_t SB = (size_t)12582912;   // 16384*768 == 12*16384*64
  u16* Xh  = ws;
  u16* Xl  = Xh + SB;
  u16* Qh  = Xl + SB;
  u16* Ql  = Qh + SB;
  u16* Kh  = Ql + SB;
  u16* Kl  = Kh + SB;
  u16* Vt  = Kl + SB;
  u16* Cc  = Vt + SB;
  u16* Wqh = Cc + SB;
  u16* Wql = Wqh + 589824;
  u16* Wkh = Wql + 589824;
  u16* Wkl = Wkh + 589824;
  u16* Wvh = Wkl + 589824;
  u16* Wot = Wvh + 589824;

  split_x_k<<<12288, 256, 0, stream>>>(x, Xh, Xl);
  pack_w_k<<<2304, 256, 0, stream>>>(Wq, Wqh, Wql, 0.125f, 1);   // 1/sqrt(D) folded into Wq
  pack_w_k<<<2304, 256, 0, stream>>>(Wk, Wkh, Wkl, 1.0f, 1);
  pack_w_k<<<2304, 256, 0, stream>>>(Wv, Wvh, Wvh, 1.0f, 0);     // lo unused
  pack_wo_k<<<192, 256, 0, stream>>>(Wo, Wot);

  gemm_qk_k<<<dim3(128,12), 256, 0, stream>>>(Xh, Xl, Wqh, Wql, Qh, Ql);
  gemm_qk_k<<<dim3(128,12), 256, 0, stream>>>(Xh, Xl, Wkh, Wkl, Kh, Kl);
  gemm_v_k <<<dim3(128,12), 256, 0, stream>>>(Xh, Wvh, Vt);
  flash_k  <<<1536, 256, 0, stream>>>(Qh, Ql, Kh, Kl, Vt, Cc);
  gemm_o_k <<<128, 256, 0, stream>>>(Cc, Wot, out);
}